// Round 5
// baseline (1160.566 us; speedup 1.0000x reference)
//
#include <hip/hip_runtime.h>

#define NPTS 80000
#define MPTS 150000
#define NDPTS 10000
#define KOFF 27
#define C3 16
#define CP 259
#define C2 64
#define CM 80
#define CO 96

typedef __attribute__((ext_vector_type(8))) short short8;
typedef __attribute__((ext_vector_type(4))) float f32x4;

__device__ inline short bf16r(float f) {
  union { float f; unsigned u; } x{f};
  unsigned r = (x.u + 0x7fffu + ((x.u >> 16) & 1u)) >> 16;
  return (short)r;
}

// ---------------------------------------------------------------------------
// Weight prep: W[k][ci][n] fp32 -> fragment-ordered bf16
// WbfF[((k*KC+q)*NT+t)*512 + lane*8 + j], B-frag element:
// ci = q*32 + (lane>>4)*8 + j, n = t*16 + (lane&15); ci >= CIN zero-padded.
// ---------------------------------------------------------------------------
__global__ void wfrag_kernel(const float* __restrict__ W, short* __restrict__ WbfF,
                             int CIN, int COUT_, int KC) {
  const int NT = COUT_ / 16;
  int i = blockIdx.x * 256 + threadIdx.x;
  int total = KOFF * KC * NT * 512;
  if (i >= total) return;
  int j = i & 7, lane = (i >> 3) & 63;
  int rest = i >> 9;
  int t = rest % NT; rest /= NT;
  int q = rest % KC;
  int k = rest / KC;
  int ci = q * 32 + (lane >> 4) * 8 + j;
  int n = t * 16 + (lane & 15);
  float v = (ci < CIN) ? W[((size_t)k * CIN + ci) * COUT_ + n] : 0.f;
  WbfF[i] = bf16r(v);
}

// ---------------------------------------------------------------------------
// Wp prep: fp32 [259][64] -> bf16 fragment-ordered [q][t][lane][8], K->288.
// ---------------------------------------------------------------------------
__global__ void wpfrag_kernel(const float* __restrict__ Wp, short* __restrict__ WpF) {
  int i = blockIdx.x * 256 + threadIdx.x;
  if (i >= 9 * 4 * 64 * 8) return;
  int j = i & 7, lane = (i >> 3) & 63, t = (i >> 9) & 3, q = i >> 11;
  int k = q * 32 + (lane >> 4) * 8 + j;
  int n = t * 16 + (lane & 15);
  WpF[i] = (k < CP) ? bf16r(Wp[(size_t)k * C2 + n]) : (short)0;
}

// ---------------------------------------------------------------------------
// Kernel 1: conv3d (16->16) + bn_relu -> y3d fp32, mix[:, :16], mixbf[:, :16].
// (round-2 version; round-3 rewrite spilled to scratch and was reverted.)
// ---------------------------------------------------------------------------
__global__ __launch_bounds__(256) void conv3d_bnrelu_kernel(
    const float* __restrict__ x3d, const int* __restrict__ nbr,
    const float* __restrict__ W3d, const float* __restrict__ g3d,
    const float* __restrict__ b3d, float* __restrict__ y3d,
    float* __restrict__ mix, short* __restrict__ mixbf)
{
  __shared__ float wS[KOFF * C3 * C3];
  __shared__ float fS[16][C3];
  const int tid = threadIdx.x;
  const int base = blockIdx.x * 16;
  for (int e = tid; e < KOFF * C3 * C3; e += 256) wS[e] = W3d[e];
  const int r = tid >> 4, c = tid & 15;
  const int row = base + r;
  float acc = 0.f;
  for (int k = 0; k < KOFF; ++k) {
    int idx = nbr[row * KOFF + k];
    float fv = (idx >= 0) ? x3d[idx * C3 + c] : 0.f;
    __syncthreads();
    fS[r][c] = fv;
    __syncthreads();
    const float* wk = &wS[k * C3 * C3];
    #pragma unroll
    for (int ci = 0; ci < C3; ++ci)
      acc = fmaf(fS[r][ci], wk[ci * C3 + c], acc);
  }
  float v = fmaxf(fmaf(acc, g3d[c], b3d[c]), 0.f);
  y3d[row * C3 + c] = v;
  mix[row * CM + c] = v;
  mixbf[row * CM + c] = bf16r(v);
}

// ---------------------------------------------------------------------------
// Kernel 2: gate/cross fusion. v2: all 32 f2d gathers issued up front
// (8KB in flight per wave), y3d staged to LDS cooperatively, 3-column tail
// parallelized across 96 threads.
// ---------------------------------------------------------------------------
__global__ __launch_bounds__(256) void gate_cross_mfma_kernel(
    const float* __restrict__ y3d, const float* __restrict__ f2d,
    const int* __restrict__ nn_idx,
    const float* __restrict__ Wg, const float* __restrict__ bg,
    const float* __restrict__ Wc, const float* __restrict__ bc,
    const short* __restrict__ WpF,
    short* __restrict__ p2dbf, float* __restrict__ cross2d)
{
  constexpr int RS = 296;
  __shared__ short g1S[32 * RS];
  __shared__ short g2S[32 * RS];
  __shared__ float yS[32][C3];
  const int tid = threadIdx.x;
  const int lane = tid & 63;
  const int w = tid >> 6;
  const int lm = lane & 15;
  const int quad = lane >> 4;
  const int base = blockIdx.x * 32;

  // zero the CP..288 pad columns
  for (int e = tid; e < 32 * 32; e += 256) {
    int r = e >> 5, cc = 256 + (e & 31);
    if (cc >= CP) {
      g1S[r * RS + cc] = 0;
      g2S[r * RS + cc] = 0;
    }
  }

  // uniform neighbor indices for all 32 rows
  int ix[32];
  #pragma unroll
  for (int r = 0; r < 32; ++r) ix[r] = nn_idx[base + r];

  // issue ALL 32 f2d gathers up front (independent, stay in flight)
  const int c = tid;
  float f[32];
  #pragma unroll
  for (int r = 0; r < 32; ++r)
    f[r] = (ix[r] >= 0) ? f2d[(size_t)ix[r] * CP + c] : 0.f;

  // tail-column gather (threads 0..95 cover r in [0,32) x cc in [0,3))
  float ftail = 0.f;
  int tr = 0, tcc = 0;
  if (tid < 96) {
    tr = tid / 3; tcc = tid - tr * 3;
    if (ix[tr] >= 0) ftail = f2d[(size_t)ix[tr] * CP + 256 + tcc];
  }

  // stage y3d rows cooperatively (contiguous 2KB)
  for (int e = tid; e < 32 * C3; e += 256)
    ((float*)yS)[e] = y3d[(size_t)base * C3 + e];

  float wg[16], wc[16];
  #pragma unroll
  for (int ci = 0; ci < 16; ++ci) {
    wg[ci] = Wg[ci * CP + c];
    wc[ci] = Wc[ci * CP + c];
  }
  const float bgv = bg[c], bcv = bc[c];

  __syncthreads();   // yS ready

  #pragma unroll
  for (int r = 0; r < 32; ++r) {
    float a1 = bgv, a2 = bcv;
    #pragma unroll
    for (int ci = 0; ci < 16; ++ci) {
      float yv = yS[r][ci];
      a1 = fmaf(yv, wg[ci], a1);
      a2 = fmaf(yv, wc[ci], a2);
    }
    g1S[r * RS + c] = bf16r(fmaxf(a1, 0.f) * f[r]);
    g2S[r * RS + c] = bf16r(fmaxf(a2, 0.f) * f[r]);
  }

  if (tid < 96) {
    const int c2 = 256 + tcc;
    float a1 = bg[c2], a2 = bc[c2];
    #pragma unroll
    for (int ci = 0; ci < 16; ++ci) {
      float yv = yS[tr][ci];
      a1 = fmaf(yv, Wg[ci * CP + c2], a1);
      a2 = fmaf(yv, Wc[ci * CP + c2], a2);
    }
    g1S[tr * RS + c2] = bf16r(fmaxf(a1, 0.f) * ftail);
    g2S[tr * RS + c2] = bf16r(fmaxf(a2, 0.f) * ftail);
  }
  __syncthreads();

  const int gsel = w & 1;
  const int mt = w >> 1;
  const short* gS = gsel ? g2S : g1S;
  f32x4 acc[4];
  #pragma unroll
  for (int t = 0; t < 4; ++t) {
    f32x4 z = {0.f, 0.f, 0.f, 0.f};
    acc[t] = z;
  }
  #pragma unroll
  for (int q = 0; q < 9; ++q) {
    short8 af = *(const short8*)&gS[(mt * 16 + lm) * RS + q * 32 + quad * 8];
    #pragma unroll
    for (int t = 0; t < 4; ++t) {
      short8 bf = *(const short8*)&WpF[(((q * 4 + t) * 64) + lane) * 8];
      acc[t] = __builtin_amdgcn_mfma_f32_16x16x32_bf16(af, bf, acc[t], 0, 0, 0);
    }
  }
  #pragma unroll
  for (int t = 0; t < 4; ++t) {
    const int cc = t * 16 + lm;
    #pragma unroll
    for (int rg = 0; rg < 4; ++rg) {
      const int row = base + mt * 16 + quad * 4 + rg;
      float v = acc[t][rg];
      if (gsel == 0)
        p2dbf[(size_t)row * C2 + cc] = bf16r(v);
      else
        cross2d[(size_t)row * C2 + cc] = v;
    }
  }
}

// ---------------------------------------------------------------------------
// Wave-autonomous no-LDS subm-conv: gather DIRECTLY into MFMA A-fragments.
// Round-5: MT is a template param.  MT=2 is the round-2 known-best (126us,
// VGPR 80, 2.32 TB/s).  MT=4 instantiated on ONE layer as a ceiling probe:
// per-wave in-flight gather bytes double; if hbm_gbps stays ~2.3 the random-
// access fabric ceiling is confirmed and convs are near their floor.
// Depth-3 rotating prefetch (27 = 9*3), no sched_barriers.
//
// MODE 0: bn_relu -> fp32    MODE 1: bn_relu -> bf16
// MODE 2: relu(bn)+res(stride 64) -> fp32 mix[:,16+c] + bf16 mixbf
// MODE 3: relu(bn+res) -> fp32 + bf16    MODE 4: relu(bn+res) -> bf16
// ---------------------------------------------------------------------------
template <int CIN, int COUT_, int MODE, int MT>
__global__ __launch_bounds__(64, 2) void conv_nolds_kernel(
    const short* __restrict__ finbf, const int* __restrict__ nbr, int nrows,
    const short* __restrict__ WbfF, const float* __restrict__ gamma,
    const float* __restrict__ beta, const float* __restrict__ resf,
    float* __restrict__ outf, short* __restrict__ outbf)
{
  constexpr int KC = (CIN + 31) / 32;   // 32-wide k-chunks per row
  constexpr int DCH = CIN / 8;          // real 16B chunks per row
  constexpr int NT = COUT_ / 16;

  const int lane = threadIdx.x;
  const int lm = lane & 15;
  const int quad = lane >> 4;
  const int base = blockIdx.x * (MT * 16);

  int rrow[MT];
  bool rok[MT];
  #pragma unroll
  for (int i = 0; i < MT; ++i) {
    rrow[i] = base + i * 16 + lm;
    rok[i] = rrow[i] < nrows;
  }

  f32x4 acc[MT][NT];
  #pragma unroll
  for (int i = 0; i < MT; ++i)
    #pragma unroll
    for (int t = 0; t < NT; ++t) {
      f32x4 z = {0.f, 0.f, 0.f, 0.f};
      acc[i][t] = z;
    }

  const short8 zero8 = {0, 0, 0, 0, 0, 0, 0, 0};

  // neighbor-index load (stride-27 across lm; L1-hot after k=0)
  auto loadIdx = [&](int (&id)[MT], int k) {
    #pragma unroll
    for (int i = 0; i < MT; ++i)
      id[i] = (k < KOFF && rok[i]) ? nbr[(size_t)rrow[i] * KOFF + k] : -1;
  };

  // gather one k-offset's A-fragments straight from global
  auto loadA = [&](short8 (&pa)[MT][KC], const int (&id)[MT]) {
    #pragma unroll
    for (int i = 0; i < MT; ++i) {
      const int safe = (id[i] < 0) ? 0 : id[i];     // in-bounds address always
      const bool ok = id[i] >= 0;
      const short* src = finbf + (size_t)safe * CIN;
      #pragma unroll
      for (int q = 0; q < KC; ++q) {
        const int ch = q * 4 + quad;
        short8 v = zero8;
        if (ch < DCH) v = *(const short8*)(src + ch * 8);
        pa[i][q] = ok ? v : zero8;
      }
    }
  };

  auto computeK = [&](const short8 (&pa)[MT][KC], int k) {
    const short* wb = WbfF + ((size_t)k * KC * NT) * 512 + lane * 8;
    #pragma unroll
    for (int q = 0; q < KC; ++q) {
      #pragma unroll
      for (int t = 0; t < NT; ++t) {
        short8 bfr = *(const short8*)(wb + (q * NT + t) * 512);
        #pragma unroll
        for (int i = 0; i < MT; ++i)
          acc[i][t] = __builtin_amdgcn_mfma_f32_16x16x32_bf16(pa[i][q], bfr,
                                                              acc[i][t], 0, 0, 0);
      }
    }
  };

  // ---- depth-3 software pipeline over k (27 = 9*3, no tail) ----
  int ia[MT], ib[MT], ic[MT];
  short8 paA[MT][KC], paB[MT][KC], paC[MT][KC];

  loadIdx(ia, 0); loadIdx(ib, 1); loadIdx(ic, 2);
  loadA(paA, ia); loadIdx(ia, 3);
  loadA(paB, ib); loadIdx(ib, 4);

  for (int kk = 0; kk < KOFF; kk += 3) {
    loadA(paC, ic); loadIdx(ic, kk + 5);
    computeK(paA, kk);
    loadA(paA, ia); loadIdx(ia, kk + 6);   // A(kk+3); k>=27 -> idx=-1 -> zeros
    computeK(paB, kk + 1);
    loadA(paB, ib); loadIdx(ib, kk + 7);   // A(kk+4)
    computeK(paC, kk + 2);
  }

  // ---- epilogue ----
  #pragma unroll
  for (int i = 0; i < MT; ++i) {
    int rbase = base + i * 16 + quad * 4;
    #pragma unroll
    for (int t = 0; t < NT; ++t) {
      int cc = t * 16 + lm;
      float g = gamma[cc], b = beta[cc];
      #pragma unroll
      for (int rg = 0; rg < 4; ++rg) {
        int row = rbase + rg;
        if (row >= nrows) continue;
        float v = acc[i][t][rg];
        if (MODE == 0) {
          outf[(size_t)row * COUT_ + cc] = fmaxf(fmaf(v, g, b), 0.f);
        } else if (MODE == 1) {
          outbf[(size_t)row * COUT_ + cc] = bf16r(fmaxf(fmaf(v, g, b), 0.f));
        } else if (MODE == 2) {
          float o = fmaxf(fmaf(v, g, b), 0.f) + resf[(size_t)row * C2 + cc];
          outf[(size_t)row * CM + 16 + cc] = o;
          outbf[(size_t)row * CM + 16 + cc] = bf16r(o);
        } else if (MODE == 3) {
          float o = fmaxf(fmaf(v, g, b) + resf[(size_t)row * COUT_ + cc], 0.f);
          outf[(size_t)row * COUT_ + cc] = o;
          outbf[(size_t)row * COUT_ + cc] = bf16r(o);
        } else {
          float o = fmaxf(fmaf(v, g, b) + resf[(size_t)row * COUT_ + cc], 0.f);
          outbf[(size_t)row * COUT_ + cc] = bf16r(o);
        }
      }
    }
  }
}

// ---------------------------------------------------------------------------
extern "C" void kernel_launch(void* const* d_in, const int* in_sizes, int n_in,
                              void* d_out, int out_size, void* d_ws, size_t ws_size,
                              hipStream_t stream) {
  const float* x3d  = (const float*)d_in[0];
  const float* f2d  = (const float*)d_in[1];
  const int*   nn   = (const int*)d_in[2];
  const int*   nbr  = (const int*)d_in[3];
  const int*   nbds = (const int*)d_in[4];
  const float* W3d  = (const float*)d_in[5];
  const float* g3d  = (const float*)d_in[6];
  const float* b3d  = (const float*)d_in[7];
  const float* Wg   = (const float*)d_in[8];
  const float* bg   = (const float*)d_in[9];
  const float* Wc   = (const float*)d_in[10];
  const float* bc   = (const float*)d_in[11];
  const float* Wp   = (const float*)d_in[12];
  const float* W2d  = (const float*)d_in[13];
  const float* g2d  = (const float*)d_in[14];
  const float* b2d  = (const float*)d_in[15];
  const float* Wm1  = (const float*)d_in[16];
  const float* gm1  = (const float*)d_in[17];
  const float* bm1  = (const float*)d_in[18];
  const float* Wm2  = (const float*)d_in[19];
  const float* gm2  = (const float*)d_in[20];
  const float* bm2  = (const float*)d_in[21];
  const float* Wa1  = (const float*)d_in[22];
  const float* ga1  = (const float*)d_in[23];
  const float* ba1  = (const float*)d_in[24];
  const float* Wa2  = (const float*)d_in[25];
  const float* ga2  = (const float*)d_in[26];
  const float* ba2  = (const float*)d_in[27];
  const float* Wds  = (const float*)d_in[28];
  const float* gds  = (const float*)d_in[29];
  const float* bds  = (const float*)d_in[30];

  const size_t N = NPTS;
  float* ws = (float*)d_ws;
  float* y3d     = ws;                    // N*16
  short* p2dbf   = (short*)(ws + N * 16); // N*64 bf16
  float* cross2d = ws + N * 48;           // N*64
  float* mix     = ws + N * 112;          // N*80
  short* mixbf   = (short*)(ws + N * 192);// N*80 bf16
  short* tmp1bf  = (short*)(ws + N * 232);// N*80 bf16
  float* hbuf    = ws + N * 272;          // N*80
  short* hbufbf  = (short*)(ws + N * 352);// N*80 bf16
  short* abufbf  = (short*)ws;            // N*80 bf16 (reuses y3d+p2dbf)
  // fragment-ordered bf16 weights at tail
  short* wtail  = (short*)(ws + N * 392);
  short* WbfF2d = wtail;                   // 27*2*4*512 = 110592
  short* WbfFm1 = WbfF2d + 110592;         // 27*3*5*512 = 207360
  short* WbfFm2 = WbfFm1 + 207360;
  short* WbfFa1 = WbfFm2 + 207360;
  short* WbfFa2 = WbfFa1 + 207360;
  short* WbfFds = WbfFa2 + 207360;         // 27*3*6*512 = 248832
  short* WpF    = WbfFds + 248832;         // 18432

  // ---- weight prep ----
  wfrag_kernel<<<(110592 + 255) / 256, 256, 0, stream>>>(W2d, WbfF2d, 64, 64, 2);
  wfrag_kernel<<<(207360 + 255) / 256, 256, 0, stream>>>(Wm1, WbfFm1, 80, 80, 3);
  wfrag_kernel<<<(207360 + 255) / 256, 256, 0, stream>>>(Wm2, WbfFm2, 80, 80, 3);
  wfrag_kernel<<<(207360 + 255) / 256, 256, 0, stream>>>(Wa1, WbfFa1, 80, 80, 3);
  wfrag_kernel<<<(207360 + 255) / 256, 256, 0, stream>>>(Wa2, WbfFa2, 80, 80, 3);
  wfrag_kernel<<<(248832 + 255) / 256, 256, 0, stream>>>(Wds, WbfFds, 80, 96, 3);
  wpfrag_kernel<<<(9 * 4 * 64 * 8 + 255) / 256, 256, 0, stream>>>(Wp, WpF);

  conv3d_bnrelu_kernel<<<NPTS / 16, 256, 0, stream>>>(x3d, nbr, W3d, g3d, b3d,
                                                      y3d, mix, mixbf);
  gate_cross_mfma_kernel<<<NPTS / 32, 256, 0, stream>>>(y3d, f2d, nn, Wg, bg,
                                                        Wc, bc, WpF, p2dbf,
                                                        cross2d);

  const int gridM2 = (NPTS + 31) / 32;    // 2500 one-wave blocks (MT=2)
  const int gridM4 = (NPTS + 63) / 64;    // 1250 one-wave blocks (MT=4)
  conv_nolds_kernel<64, 64, 2, 2><<<gridM2, 64, 0, stream>>>(
      p2dbf, nbr, NPTS, WbfF2d, g2d, b2d, cross2d, mix, mixbf);
  conv_nolds_kernel<80, 80, 1, 2><<<gridM2, 64, 0, stream>>>(
      mixbf, nbr, NPTS, WbfFm1, gm1, bm1, nullptr, nullptr, tmp1bf);
  // MT=4 ceiling probe on layer 3
  conv_nolds_kernel<80, 80, 3, 4><<<gridM4, 64, 0, stream>>>(
      tmp1bf, nbr, NPTS, WbfFm2, gm2, bm2, mix, hbuf, hbufbf);
  conv_nolds_kernel<80, 80, 1, 2><<<gridM2, 64, 0, stream>>>(
      hbufbf, nbr, NPTS, WbfFa1, ga1, ba1, nullptr, nullptr, tmp1bf);
  conv_nolds_kernel<80, 80, 4, 2><<<gridM2, 64, 0, stream>>>(
      tmp1bf, nbr, NPTS, WbfFa2, ga2, ba2, hbuf, nullptr, abufbf);

  const int gridDS = (NDPTS + 31) / 32;   // 313 (MT=2)
  conv_nolds_kernel<80, 96, 0, 2><<<gridDS, 64, 0, stream>>>(
      abufbf, nbds, NDPTS, WbfFds, gds, bds, nullptr, (float*)d_out, nullptr);
}

// Round 6
// 1093.292 us; speedup vs baseline: 1.0615x; 1.0615x over previous
//
#include <hip/hip_runtime.h>

#define NPTS 80000
#define MPTS 150000
#define NDPTS 10000
#define KOFF 27
#define C3 16
#define CP 259
#define C2 64
#define CM 80
#define CO 96

typedef __attribute__((ext_vector_type(8))) short short8;
typedef __attribute__((ext_vector_type(4))) float f32x4;

__device__ inline short bf16r(float f) {
  union { float f; unsigned u; } x{f};
  unsigned r = (x.u + 0x7fffu + ((x.u >> 16) & 1u)) >> 16;
  return (short)r;
}

typedef __attribute__((address_space(1))) const unsigned int g_u32;
typedef __attribute__((address_space(3))) unsigned int l_u32;
__device__ __forceinline__ void gload_lds16(const void* g, void* l) {
  // per-lane global src; LDS dest = wave-uniform base + lane*16
  __builtin_amdgcn_global_load_lds((g_u32*)g, (l_u32*)l, 16, 0, 0);
}

// ---------------------------------------------------------------------------
// Weight prep: W[k][ci][n] fp32 -> fragment-ordered bf16
// WbfF[((k*KC+q)*NT+t)*512 + lane*8 + j], B-frag element:
// ci = q*32 + (lane>>4)*8 + j, n = t*16 + (lane&15); ci >= CIN zero-padded.
// ---------------------------------------------------------------------------
__global__ void wfrag_kernel(const float* __restrict__ W, short* __restrict__ WbfF,
                             int CIN, int COUT_, int KC) {
  const int NT = COUT_ / 16;
  int i = blockIdx.x * 256 + threadIdx.x;
  int total = KOFF * KC * NT * 512;
  if (i >= total) return;
  int j = i & 7, lane = (i >> 3) & 63;
  int rest = i >> 9;
  int t = rest % NT; rest /= NT;
  int q = rest % KC;
  int k = rest / KC;
  int ci = q * 32 + (lane >> 4) * 8 + j;
  int n = t * 16 + (lane & 15);
  float v = (ci < CIN) ? W[((size_t)k * CIN + ci) * COUT_ + n] : 0.f;
  WbfF[i] = bf16r(v);
}

// ---------------------------------------------------------------------------
// Wp prep: fp32 [259][64] -> bf16 fragment-ordered [q][t][lane][8], K->288.
// ---------------------------------------------------------------------------
__global__ void wpfrag_kernel(const float* __restrict__ Wp, short* __restrict__ WpF) {
  int i = blockIdx.x * 256 + threadIdx.x;
  if (i >= 9 * 4 * 64 * 8) return;
  int j = i & 7, lane = (i >> 3) & 63, t = (i >> 9) & 3, q = i >> 11;
  int k = q * 32 + (lane >> 4) * 8 + j;
  int n = t * 16 + (lane & 15);
  WpF[i] = (k < CP) ? bf16r(Wp[(size_t)k * C2 + n]) : (short)0;
}

// ---------------------------------------------------------------------------
// Kernel 1: conv3d (16->16) + bn_relu (round-2 version, known good).
// ---------------------------------------------------------------------------
__global__ __launch_bounds__(256) void conv3d_bnrelu_kernel(
    const float* __restrict__ x3d, const int* __restrict__ nbr,
    const float* __restrict__ W3d, const float* __restrict__ g3d,
    const float* __restrict__ b3d, float* __restrict__ y3d,
    float* __restrict__ mix, short* __restrict__ mixbf)
{
  __shared__ float wS[KOFF * C3 * C3];
  __shared__ float fS[16][C3];
  const int tid = threadIdx.x;
  const int base = blockIdx.x * 16;
  for (int e = tid; e < KOFF * C3 * C3; e += 256) wS[e] = W3d[e];
  const int r = tid >> 4, c = tid & 15;
  const int row = base + r;
  float acc = 0.f;
  for (int k = 0; k < KOFF; ++k) {
    int idx = nbr[row * KOFF + k];
    float fv = (idx >= 0) ? x3d[idx * C3 + c] : 0.f;
    __syncthreads();
    fS[r][c] = fv;
    __syncthreads();
    const float* wk = &wS[k * C3 * C3];
    #pragma unroll
    for (int ci = 0; ci < C3; ++ci)
      acc = fmaf(fS[r][ci], wk[ci * C3 + c], acc);
  }
  float v = fmaxf(fmaf(acc, g3d[c], b3d[c]), 0.f);
  y3d[row * C3 + c] = v;
  mix[row * CM + c] = v;
  mixbf[row * CM + c] = bf16r(v);
}

// ---------------------------------------------------------------------------
// Kernel 2: gate/cross fusion (round-4 version).
// ---------------------------------------------------------------------------
__global__ __launch_bounds__(256) void gate_cross_mfma_kernel(
    const float* __restrict__ y3d, const float* __restrict__ f2d,
    const int* __restrict__ nn_idx,
    const float* __restrict__ Wg, const float* __restrict__ bg,
    const float* __restrict__ Wc, const float* __restrict__ bc,
    const short* __restrict__ WpF,
    short* __restrict__ p2dbf, float* __restrict__ cross2d)
{
  constexpr int RS = 296;
  __shared__ short g1S[32 * RS];
  __shared__ short g2S[32 * RS];
  __shared__ float yS[32][C3];
  const int tid = threadIdx.x;
  const int lane = tid & 63;
  const int w = tid >> 6;
  const int lm = lane & 15;
  const int quad = lane >> 4;
  const int base = blockIdx.x * 32;

  for (int e = tid; e < 32 * 32; e += 256) {
    int r = e >> 5, cc = 256 + (e & 31);
    if (cc >= CP) {
      g1S[r * RS + cc] = 0;
      g2S[r * RS + cc] = 0;
    }
  }

  int ix[32];
  #pragma unroll
  for (int r = 0; r < 32; ++r) ix[r] = nn_idx[base + r];

  const int c = tid;
  float f[32];
  #pragma unroll
  for (int r = 0; r < 32; ++r)
    f[r] = (ix[r] >= 0) ? f2d[(size_t)ix[r] * CP + c] : 0.f;

  float ftail = 0.f;
  int tr = 0, tcc = 0;
  if (tid < 96) {
    tr = tid / 3; tcc = tid - tr * 3;
    if (ix[tr] >= 0) ftail = f2d[(size_t)ix[tr] * CP + 256 + tcc];
  }

  for (int e = tid; e < 32 * C3; e += 256)
    ((float*)yS)[e] = y3d[(size_t)base * C3 + e];

  float wg[16], wc[16];
  #pragma unroll
  for (int ci = 0; ci < 16; ++ci) {
    wg[ci] = Wg[ci * CP + c];
    wc[ci] = Wc[ci * CP + c];
  }
  const float bgv = bg[c], bcv = bc[c];

  __syncthreads();

  #pragma unroll
  for (int r = 0; r < 32; ++r) {
    float a1 = bgv, a2 = bcv;
    #pragma unroll
    for (int ci = 0; ci < 16; ++ci) {
      float yv = yS[r][ci];
      a1 = fmaf(yv, wg[ci], a1);
      a2 = fmaf(yv, wc[ci], a2);
    }
    g1S[r * RS + c] = bf16r(fmaxf(a1, 0.f) * f[r]);
    g2S[r * RS + c] = bf16r(fmaxf(a2, 0.f) * f[r]);
  }

  if (tid < 96) {
    const int c2 = 256 + tcc;
    float a1 = bg[c2], a2 = bc[c2];
    #pragma unroll
    for (int ci = 0; ci < 16; ++ci) {
      float yv = yS[tr][ci];
      a1 = fmaf(yv, Wg[ci * CP + c2], a1);
      a2 = fmaf(yv, Wc[ci * CP + c2], a2);
    }
    g1S[tr * RS + c2] = bf16r(fmaxf(a1, 0.f) * ftail);
    g2S[tr * RS + c2] = bf16r(fmaxf(a2, 0.f) * ftail);
  }
  __syncthreads();

  const int gsel = w & 1;
  const int mt = w >> 1;
  const short* gS = gsel ? g2S : g1S;
  f32x4 acc[4];
  #pragma unroll
  for (int t = 0; t < 4; ++t) {
    f32x4 z = {0.f, 0.f, 0.f, 0.f};
    acc[t] = z;
  }
  #pragma unroll
  for (int q = 0; q < 9; ++q) {
    short8 af = *(const short8*)&gS[(mt * 16 + lm) * RS + q * 32 + quad * 8];
    #pragma unroll
    for (int t = 0; t < 4; ++t) {
      short8 bf = *(const short8*)&WpF[(((q * 4 + t) * 64) + lane) * 8];
      acc[t] = __builtin_amdgcn_mfma_f32_16x16x32_bf16(af, bf, acc[t], 0, 0, 0);
    }
  }
  #pragma unroll
  for (int t = 0; t < 4; ++t) {
    const int cc = t * 16 + lm;
    #pragma unroll
    for (int rg = 0; rg < 4; ++rg) {
      const int row = base + mt * 16 + quad * 4 + rg;
      float v = acc[t][rg];
      if (gsel == 0)
        p2dbf[(size_t)row * C2 + cc] = bf16r(v);
      else
        cross2d[(size_t)row * C2 + cc] = v;
    }
  }
}

// ---------------------------------------------------------------------------
// conv_glds: LDS-parked deep-prefetch subm-conv, NO barriers.
//
// Diagnosis from rounds 2-5: vmcnt retires IN ISSUE ORDER, so the per-iter
// B-fragment loads (fast, L2) issued after A-gather prefetches (slow, HBM)
// force every older A-prefetch to retire at B's use-wait -> all register
// pipelines collapsed to depth ~0-1 (~8KB/CU in flight -> 2.3 TB/s).
//
// Fix: stage BOTH A-gathers and B-fragments for k via global_load_lds into a
// wave-private LDS slot, D=2 slots ahead, as ONE issue group; consume with a
// counted `s_waitcnt vmcnt(WN)` (WN = one slot's loads still in flight).
// In-flight state costs zero VGPRs (cannot be re-sunk by the scheduler) and
// no fast load ever queues behind a slow one.  Single wave per block owns
// its buffers -> no s_barrier -> no compiler vmcnt(0) drain.
// nbr indices are pre-staged to LDS so the k-loop's ONLY vmem ops are the
// counted global_load_lds (keeps the vmcnt arithmetic exact).
//
// MODE 0: bn_relu -> fp32    MODE 1: bn_relu -> bf16
// MODE 2: relu(bn)+res(stride 64) -> fp32 mix[:,16+c] + bf16 mixbf
// MODE 3: relu(bn+res) -> fp32 + bf16    MODE 4: relu(bn+res) -> bf16
// ---------------------------------------------------------------------------
template <int CIN, int COUT_, int MODE>
__global__ __launch_bounds__(64, 1) void conv_glds_kernel(
    const short* __restrict__ finbf, const int* __restrict__ nbr, int nrows,
    const short* __restrict__ WbfF, const float* __restrict__ gamma,
    const float* __restrict__ beta, const float* __restrict__ resf,
    float* __restrict__ outf, short* __restrict__ outbf)
{
  constexpr int KC = (CIN + 31) / 32;   // 32-wide k-chunks per row
  constexpr int DCH = CIN / 8;          // real 16B chunks per row
  constexpr int NT = COUT_ / 16;
  constexpr int MT = 2;
  constexpr int WN = MT * KC + KC * NT; // loads per slot (12 / 21 / 24)

  __shared__ short8 aS[2 * MT * KC * 64];   // A slots: 2 x MT x KC x 1024B
  __shared__ short8 bS[2 * KC * NT * 64];   // B slots: 2 x KC x NT x 1024B
  __shared__ int nbrS[32 * KOFF];

  const int lane = threadIdx.x;
  const int lm = lane & 15;
  const int quad = lane >> 4;
  const int base = blockIdx.x * 32;

  // ---- cooperative nbr prefetch into LDS (OOB rows -> -1) ----
  for (int e = lane; e < 32 * KOFF; e += 64) {
    int r = e / KOFF;
    int row = base + r;
    nbrS[e] = (row < nrows) ? nbr[(size_t)row * KOFF + (e - r * KOFF)] : -1;
  }
  // single wave per block: lgkmcnt orders ds_write -> ds_read; no barrier.

  f32x4 acc[MT][NT];
  #pragma unroll
  for (int i = 0; i < MT; ++i)
    #pragma unroll
    for (int t = 0; t < NT; ++t) {
      f32x4 z = {0.f, 0.f, 0.f, 0.f};
      acc[i][t] = z;
    }

  auto readIdx = [&](int k, int (&id)[MT]) {
    #pragma unroll
    for (int i = 0; i < MT; ++i)
      id[i] = (k < KOFF) ? nbrS[(i * 16 + lm) * KOFF + k] : -1;
  };

  // stage slot (k2&1): A-gathers (MT*KC) + B-frags (KC*NT), all 16B/lane.
  auto stage = [&](int k2, const int (&id)[MT]) {
    const int slot = k2 & 1;
    #pragma unroll
    for (int i = 0; i < MT; ++i) {
      const int safe = (id[i] < 0) ? 0 : id[i];
      const short* srow = finbf + (size_t)safe * CIN;
      #pragma unroll
      for (int q = 0; q < KC; ++q) {
        const int ch = q * 4 + quad;
        const int chs = (ch < DCH) ? ch : (DCH - 1);  // in-bounds; masked later
        gload_lds16(srow + chs * 8, &aS[((slot * MT + i) * KC + q) * 64]);
      }
    }
    const short* wb = WbfF + (size_t)k2 * (KC * NT * 512) + lane * 8;
    #pragma unroll
    for (int q = 0; q < KC; ++q)
      #pragma unroll
      for (int t = 0; t < NT; ++t)
        gload_lds16(wb + (q * NT + t) * 512, &bS[((slot * KC + q) * NT + t) * 64]);
  };

  auto waitSlot = [&]() {
    if constexpr (WN == 12)      asm volatile("s_waitcnt vmcnt(12)" ::: "memory");
    else if constexpr (WN == 21) asm volatile("s_waitcnt vmcnt(21)" ::: "memory");
    else                         asm volatile("s_waitcnt vmcnt(24)" ::: "memory");
  };

  const short8 zero8 = {0, 0, 0, 0, 0, 0, 0, 0};

  // ---- prologue: stage k=0,1 ----
  {
    int id0[MT], id1[MT];
    readIdx(0, id0);
    readIdx(1, id1);
    stage(0, id0);
    stage(1, id1);
  }

  // ---- main loop ----
  for (int k = 0; k < KOFF - 1; ++k) {
    const int slot = k & 1;
    waitSlot();                      // slot k's loads landed (slot k+1 in flight)
    short8 va[MT][KC];
    #pragma unroll
    for (int i = 0; i < MT; ++i)
      #pragma unroll
      for (int q = 0; q < KC; ++q)
        va[i][q] = aS[((slot * MT + i) * KC + q) * 64 + lane];
    short8 vb[KC][NT];
    #pragma unroll
    for (int q = 0; q < KC; ++q)
      #pragma unroll
      for (int t = 0; t < NT; ++t)
        vb[q][t] = bS[((slot * KC + q) * NT + t) * 64 + lane];
    int ikc[MT], ikn[MT];
    readIdx(k, ikc);                 // mask for this k
    readIdx(k + 2, ikn);             // indices for restage
    asm volatile("s_waitcnt lgkmcnt(0)" ::: "memory");
    __builtin_amdgcn_sched_barrier(0);   // rule 18: pin MFMA/VALU below the wait
    // mask invalid neighbors / pad chunks
    #pragma unroll
    for (int i = 0; i < MT; ++i) {
      const bool okr = ikc[i] >= 0;
      #pragma unroll
      for (int q = 0; q < KC; ++q) {
        const bool okc = okr && ((q * 4 + quad) < DCH);
        va[i][q] = okc ? va[i][q] : zero8;
      }
    }
    if (k + 2 < KOFF) stage(k + 2, ikn);   // refill same slot (reads retired)
    #pragma unroll
    for (int q = 0; q < KC; ++q)
      #pragma unroll
      for (int t = 0; t < NT; ++t)
        #pragma unroll
        for (int i = 0; i < MT; ++i)
          acc[i][t] = __builtin_amdgcn_mfma_f32_16x16x32_bf16(va[i][q], vb[q][t],
                                                              acc[i][t], 0, 0, 0);
  }
  // ---- tail iter k = 26 (drain) ----
  {
    const int k = KOFF - 1;
    const int slot = k & 1;
    asm volatile("s_waitcnt vmcnt(0)" ::: "memory");
    short8 va[MT][KC];
    #pragma unroll
    for (int i = 0; i < MT; ++i)
      #pragma unroll
      for (int q = 0; q < KC; ++q)
        va[i][q] = aS[((slot * MT + i) * KC + q) * 64 + lane];
    short8 vb[KC][NT];
    #pragma unroll
    for (int q = 0; q < KC; ++q)
      #pragma unroll
      for (int t = 0; t < NT; ++t)
        vb[q][t] = bS[((slot * KC + q) * NT + t) * 64 + lane];
    int ikc[MT];
    readIdx(k, ikc);
    asm volatile("s_waitcnt lgkmcnt(0)" ::: "memory");
    __builtin_amdgcn_sched_barrier(0);
    #pragma unroll
    for (int i = 0; i < MT; ++i) {
      const bool okr = ikc[i] >= 0;
      #pragma unroll
      for (int q = 0; q < KC; ++q) {
        const bool okc = okr && ((q * 4 + quad) < DCH);
        va[i][q] = okc ? va[i][q] : zero8;
      }
    }
    #pragma unroll
    for (int q = 0; q < KC; ++q)
      #pragma unroll
      for (int t = 0; t < NT; ++t)
        #pragma unroll
        for (int i = 0; i < MT; ++i)
          acc[i][t] = __builtin_amdgcn_mfma_f32_16x16x32_bf16(va[i][q], vb[q][t],
                                                              acc[i][t], 0, 0, 0);
  }

  // ---- epilogue ----
  #pragma unroll
  for (int i = 0; i < MT; ++i) {
    int rbase = base + i * 16 + quad * 4;
    #pragma unroll
    for (int t = 0; t < NT; ++t) {
      int cc = t * 16 + lm;
      float g = gamma[cc], b = beta[cc];
      #pragma unroll
      for (int rg = 0; rg < 4; ++rg) {
        int row = rbase + rg;
        if (row >= nrows) continue;
        float v = acc[i][t][rg];
        if (MODE == 0) {
          outf[(size_t)row * COUT_ + cc] = fmaxf(fmaf(v, g, b), 0.f);
        } else if (MODE == 1) {
          outbf[(size_t)row * COUT_ + cc] = bf16r(fmaxf(fmaf(v, g, b), 0.f));
        } else if (MODE == 2) {
          float o = fmaxf(fmaf(v, g, b), 0.f) + resf[(size_t)row * C2 + cc];
          outf[(size_t)row * CM + 16 + cc] = o;
          outbf[(size_t)row * CM + 16 + cc] = bf16r(o);
        } else if (MODE == 3) {
          float o = fmaxf(fmaf(v, g, b) + resf[(size_t)row * COUT_ + cc], 0.f);
          outf[(size_t)row * COUT_ + cc] = o;
          outbf[(size_t)row * COUT_ + cc] = bf16r(o);
        } else {
          float o = fmaxf(fmaf(v, g, b) + resf[(size_t)row * COUT_ + cc], 0.f);
          outbf[(size_t)row * COUT_ + cc] = bf16r(o);
        }
      }
    }
  }
}

// ---------------------------------------------------------------------------
extern "C" void kernel_launch(void* const* d_in, const int* in_sizes, int n_in,
                              void* d_out, int out_size, void* d_ws, size_t ws_size,
                              hipStream_t stream) {
  const float* x3d  = (const float*)d_in[0];
  const float* f2d  = (const float*)d_in[1];
  const int*   nn   = (const int*)d_in[2];
  const int*   nbr  = (const int*)d_in[3];
  const int*   nbds = (const int*)d_in[4];
  const float* W3d  = (const float*)d_in[5];
  const float* g3d  = (const float*)d_in[6];
  const float* b3d  = (const float*)d_in[7];
  const float* Wg   = (const float*)d_in[8];
  const float* bg   = (const float*)d_in[9];
  const float* Wc   = (const float*)d_in[10];
  const float* bc   = (const float*)d_in[11];
  const float* Wp   = (const float*)d_in[12];
  const float* W2d  = (const float*)d_in[13];
  const float* g2d  = (const float*)d_in[14];
  const float* b2d  = (const float*)d_in[15];
  const float* Wm1  = (const float*)d_in[16];
  const float* gm1  = (const float*)d_in[17];
  const float* bm1  = (const float*)d_in[18];
  const float* Wm2  = (const float*)d_in[19];
  const float* gm2  = (const float*)d_in[20];
  const float* bm2  = (const float*)d_in[21];
  const float* Wa1  = (const float*)d_in[22];
  const float* ga1  = (const float*)d_in[23];
  const float* ba1  = (const float*)d_in[24];
  const float* Wa2  = (const float*)d_in[25];
  const float* ga2  = (const float*)d_in[26];
  const float* ba2  = (const float*)d_in[27];
  const float* Wds  = (const float*)d_in[28];
  const float* gds  = (const float*)d_in[29];
  const float* bds  = (const float*)d_in[30];

  const size_t N = NPTS;
  float* ws = (float*)d_ws;
  float* y3d     = ws;                    // N*16
  short* p2dbf   = (short*)(ws + N * 16); // N*64 bf16
  float* cross2d = ws + N * 48;           // N*64
  float* mix     = ws + N * 112;          // N*80
  short* mixbf   = (short*)(ws + N * 192);// N*80 bf16
  short* tmp1bf  = (short*)(ws + N * 232);// N*80 bf16
  float* hbuf    = ws + N * 272;          // N*80
  short* hbufbf  = (short*)(ws + N * 352);// N*80 bf16
  short* abufbf  = (short*)ws;            // N*80 bf16 (reuses y3d+p2dbf)
  // fragment-ordered bf16 weights at tail
  short* wtail  = (short*)(ws + N * 392);
  short* WbfF2d = wtail;                   // 27*2*4*512 = 110592
  short* WbfFm1 = WbfF2d + 110592;         // 27*3*5*512 = 207360
  short* WbfFm2 = WbfFm1 + 207360;
  short* WbfFa1 = WbfFm2 + 207360;
  short* WbfFa2 = WbfFa1 + 207360;
  short* WbfFds = WbfFa2 + 207360;         // 27*3*6*512 = 248832
  short* WpF    = WbfFds + 248832;         // 18432

  // ---- weight prep ----
  wfrag_kernel<<<(110592 + 255) / 256, 256, 0, stream>>>(W2d, WbfF2d, 64, 64, 2);
  wfrag_kernel<<<(207360 + 255) / 256, 256, 0, stream>>>(Wm1, WbfFm1, 80, 80, 3);
  wfrag_kernel<<<(207360 + 255) / 256, 256, 0, stream>>>(Wm2, WbfFm2, 80, 80, 3);
  wfrag_kernel<<<(207360 + 255) / 256, 256, 0, stream>>>(Wa1, WbfFa1, 80, 80, 3);
  wfrag_kernel<<<(207360 + 255) / 256, 256, 0, stream>>>(Wa2, WbfFa2, 80, 80, 3);
  wfrag_kernel<<<(248832 + 255) / 256, 256, 0, stream>>>(Wds, WbfFds, 80, 96, 3);
  wpfrag_kernel<<<(9 * 4 * 64 * 8 + 255) / 256, 256, 0, stream>>>(Wp, WpF);

  conv3d_bnrelu_kernel<<<NPTS / 16, 256, 0, stream>>>(x3d, nbr, W3d, g3d, b3d,
                                                      y3d, mix, mixbf);
  gate_cross_mfma_kernel<<<NPTS / 32, 256, 0, stream>>>(y3d, f2d, nn, Wg, bg,
                                                        Wc, bc, WpF, p2dbf,
                                                        cross2d);

  const int gridW = (NPTS + 31) / 32;    // 2500 one-wave blocks
  conv_glds_kernel<64, 64, 2><<<gridW, 64, 0, stream>>>(
      p2dbf, nbr, NPTS, WbfF2d, g2d, b2d, cross2d, mix, mixbf);
  conv_glds_kernel<80, 80, 1><<<gridW, 64, 0, stream>>>(
      mixbf, nbr, NPTS, WbfFm1, gm1, bm1, nullptr, nullptr, tmp1bf);
  conv_glds_kernel<80, 80, 3><<<gridW, 64, 0, stream>>>(
      tmp1bf, nbr, NPTS, WbfFm2, gm2, bm2, mix, hbuf, hbufbf);
  conv_glds_kernel<80, 80, 1><<<gridW, 64, 0, stream>>>(
      hbufbf, nbr, NPTS, WbfFa1, ga1, ba1, nullptr, nullptr, tmp1bf);
  conv_glds_kernel<80, 80, 4><<<gridW, 64, 0, stream>>>(
      tmp1bf, nbr, NPTS, WbfFa2, ga2, ba2, hbuf, nullptr, abufbf);

  const int gridDS = (NDPTS + 31) / 32;  // 313
  conv_glds_kernel<80, 96, 0><<<gridDS, 64, 0, stream>>>(
      abufbf, nbds, NDPTS, WbfFds, gds, bds, nullptr, (float*)d_out, nullptr);
}

// Round 7
// 1014.894 us; speedup vs baseline: 1.1435x; 1.0772x over previous
//
#include <hip/hip_runtime.h>

#define NPTS 80000
#define MPTS 150000
#define NDPTS 10000
#define KOFF 27
#define C3 16
#define CP 259
#define C2 64
#define CM 80
#define CO 96

typedef __attribute__((ext_vector_type(8))) short short8;
typedef __attribute__((ext_vector_type(4))) float f32x4;

__device__ inline short bf16r(float f) {
  union { float f; unsigned u; } x{f};
  unsigned r = (x.u + 0x7fffu + ((x.u >> 16) & 1u)) >> 16;
  return (short)r;
}

// ---------------------------------------------------------------------------
// Weight prep: W[k][ci][n] fp32 -> fragment-ordered bf16
// WbfF[((k*KC+q)*NT+t)*512 + lane*8 + j], B-frag element:
// ci = q*32 + (lane>>4)*8 + j, n = t*16 + (lane&15); ci >= CIN zero-padded.
// ---------------------------------------------------------------------------
__global__ void wfrag_kernel(const float* __restrict__ W, short* __restrict__ WbfF,
                             int CIN, int COUT_, int KC) {
  const int NT = COUT_ / 16;
  int i = blockIdx.x * 256 + threadIdx.x;
  int total = KOFF * KC * NT * 512;
  if (i >= total) return;
  int j = i & 7, lane = (i >> 3) & 63;
  int rest = i >> 9;
  int t = rest % NT; rest /= NT;
  int q = rest % KC;
  int k = rest / KC;
  int ci = q * 32 + (lane >> 4) * 8 + j;
  int n = t * 16 + (lane & 15);
  float v = (ci < CIN) ? W[((size_t)k * CIN + ci) * COUT_ + n] : 0.f;
  WbfF[i] = bf16r(v);
}

// ---------------------------------------------------------------------------
// Wp prep: fp32 [259][64] -> bf16 fragment-ordered [q][t][lane][8], K->288.
// ---------------------------------------------------------------------------
__global__ void wpfrag_kernel(const float* __restrict__ Wp, short* __restrict__ WpF) {
  int i = blockIdx.x * 256 + threadIdx.x;
  if (i >= 9 * 4 * 64 * 8) return;
  int j = i & 7, lane = (i >> 3) & 63, t = (i >> 9) & 3, q = i >> 11;
  int k = q * 32 + (lane >> 4) * 8 + j;
  int n = t * 16 + (lane & 15);
  WpF[i] = (k < CP) ? bf16r(Wp[(size_t)k * C2 + n]) : (short)0;
}

// ---------------------------------------------------------------------------
// Kernel 1: conv3d (16->16) + bn_relu (round-2 version, known good).
// ---------------------------------------------------------------------------
__global__ __launch_bounds__(256) void conv3d_bnrelu_kernel(
    const float* __restrict__ x3d, const int* __restrict__ nbr,
    const float* __restrict__ W3d, const float* __restrict__ g3d,
    const float* __restrict__ b3d, float* __restrict__ y3d,
    float* __restrict__ mix, short* __restrict__ mixbf)
{
  __shared__ float wS[KOFF * C3 * C3];
  __shared__ float fS[16][C3];
  const int tid = threadIdx.x;
  const int base = blockIdx.x * 16;
  for (int e = tid; e < KOFF * C3 * C3; e += 256) wS[e] = W3d[e];
  const int r = tid >> 4, c = tid & 15;
  const int row = base + r;
  float acc = 0.f;
  for (int k = 0; k < KOFF; ++k) {
    int idx = nbr[row * KOFF + k];
    float fv = (idx >= 0) ? x3d[idx * C3 + c] : 0.f;
    __syncthreads();
    fS[r][c] = fv;
    __syncthreads();
    const float* wk = &wS[k * C3 * C3];
    #pragma unroll
    for (int ci = 0; ci < C3; ++ci)
      acc = fmaf(fS[r][ci], wk[ci * C3 + c], acc);
  }
  float v = fmaxf(fmaf(acc, g3d[c], b3d[c]), 0.f);
  y3d[row * C3 + c] = v;
  mix[row * CM + c] = v;
  mixbf[row * CM + c] = bf16r(v);
}

// ---------------------------------------------------------------------------
// Kernel 2: gate/cross fusion (round-4 version: 32 upfront f2d gathers,
// LDS-staged y3d, parallelized 3-column tail).
// ---------------------------------------------------------------------------
__global__ __launch_bounds__(256) void gate_cross_mfma_kernel(
    const float* __restrict__ y3d, const float* __restrict__ f2d,
    const int* __restrict__ nn_idx,
    const float* __restrict__ Wg, const float* __restrict__ bg,
    const float* __restrict__ Wc, const float* __restrict__ bc,
    const short* __restrict__ WpF,
    short* __restrict__ p2dbf, float* __restrict__ cross2d)
{
  constexpr int RS = 296;
  __shared__ short g1S[32 * RS];
  __shared__ short g2S[32 * RS];
  __shared__ float yS[32][C3];
  const int tid = threadIdx.x;
  const int lane = tid & 63;
  const int w = tid >> 6;
  const int lm = lane & 15;
  const int quad = lane >> 4;
  const int base = blockIdx.x * 32;

  for (int e = tid; e < 32 * 32; e += 256) {
    int r = e >> 5, cc = 256 + (e & 31);
    if (cc >= CP) {
      g1S[r * RS + cc] = 0;
      g2S[r * RS + cc] = 0;
    }
  }

  int ix[32];
  #pragma unroll
  for (int r = 0; r < 32; ++r) ix[r] = nn_idx[base + r];

  const int c = tid;
  float f[32];
  #pragma unroll
  for (int r = 0; r < 32; ++r)
    f[r] = (ix[r] >= 0) ? f2d[(size_t)ix[r] * CP + c] : 0.f;

  float ftail = 0.f;
  int tr = 0, tcc = 0;
  if (tid < 96) {
    tr = tid / 3; tcc = tid - tr * 3;
    if (ix[tr] >= 0) ftail = f2d[(size_t)ix[tr] * CP + 256 + tcc];
  }

  for (int e = tid; e < 32 * C3; e += 256)
    ((float*)yS)[e] = y3d[(size_t)base * C3 + e];

  float wg[16], wc[16];
  #pragma unroll
  for (int ci = 0; ci < 16; ++ci) {
    wg[ci] = Wg[ci * CP + c];
    wc[ci] = Wc[ci * CP + c];
  }
  const float bgv = bg[c], bcv = bc[c];

  __syncthreads();

  #pragma unroll
  for (int r = 0; r < 32; ++r) {
    float a1 = bgv, a2 = bcv;
    #pragma unroll
    for (int ci = 0; ci < 16; ++ci) {
      float yv = yS[r][ci];
      a1 = fmaf(yv, wg[ci], a1);
      a2 = fmaf(yv, wc[ci], a2);
    }
    g1S[r * RS + c] = bf16r(fmaxf(a1, 0.f) * f[r]);
    g2S[r * RS + c] = bf16r(fmaxf(a2, 0.f) * f[r]);
  }

  if (tid < 96) {
    const int c2 = 256 + tcc;
    float a1 = bg[c2], a2 = bc[c2];
    #pragma unroll
    for (int ci = 0; ci < 16; ++ci) {
      float yv = yS[tr][ci];
      a1 = fmaf(yv, Wg[ci * CP + c2], a1);
      a2 = fmaf(yv, Wc[ci * CP + c2], a2);
    }
    g1S[tr * RS + c2] = bf16r(fmaxf(a1, 0.f) * ftail);
    g2S[tr * RS + c2] = bf16r(fmaxf(a2, 0.f) * ftail);
  }
  __syncthreads();

  const int gsel = w & 1;
  const int mt = w >> 1;
  const short* gS = gsel ? g2S : g1S;
  f32x4 acc[4];
  #pragma unroll
  for (int t = 0; t < 4; ++t) {
    f32x4 z = {0.f, 0.f, 0.f, 0.f};
    acc[t] = z;
  }
  #pragma unroll
  for (int q = 0; q < 9; ++q) {
    short8 af = *(const short8*)&gS[(mt * 16 + lm) * RS + q * 32 + quad * 8];
    #pragma unroll
    for (int t = 0; t < 4; ++t) {
      short8 bf = *(const short8*)&WpF[(((q * 4 + t) * 64) + lane) * 8];
      acc[t] = __builtin_amdgcn_mfma_f32_16x16x32_bf16(af, bf, acc[t], 0, 0, 0);
    }
  }
  #pragma unroll
  for (int t = 0; t < 4; ++t) {
    const int cc = t * 16 + lm;
    #pragma unroll
    for (int rg = 0; rg < 4; ++rg) {
      const int row = base + mt * 16 + quad * 4 + rg;
      float v = acc[t][rg];
      if (gsel == 0)
        p2dbf[(size_t)row * C2 + cc] = bf16r(v);
      else
        cross2d[(size_t)row * C2 + cc] = v;
    }
  }
}

// ---------------------------------------------------------------------------
// Wave-autonomous no-LDS subm-conv: gather DIRECTLY into MFMA A-fragments.
// Round-7 consolidation: MT=2 (round-2's 126us config — session best per-conv)
// for all big layers; MT=1 for the small ds conv (625 blocks > 313 for tail
// occupancy).  Depth-3 rotating prefetch (27 = 9*3), no sched_barriers, no
// LDS (r6: LDS parking triggers compiler vmcnt(0) on the ds_read hazard and
// cuts residency; r3: sched_barriers + deep pipelines spill).
// Evidence r2/r4/r5/r6: random-gather BW saturates at ~2.1-2.3 TB/s across a
// 1.5x concurrency range -> fabric-limited; this structure sits at that
// ceiling with minimal overhead.
//
// MODE 0: bn_relu -> fp32    MODE 1: bn_relu -> bf16
// MODE 2: relu(bn)+res(stride 64) -> fp32 mix[:,16+c] + bf16 mixbf
// MODE 3: relu(bn+res) -> fp32 + bf16    MODE 4: relu(bn+res) -> bf16
// ---------------------------------------------------------------------------
template <int CIN, int COUT_, int MODE, int MT>
__global__ __launch_bounds__(64, 2) void conv_nolds_kernel(
    const short* __restrict__ finbf, const int* __restrict__ nbr, int nrows,
    const short* __restrict__ WbfF, const float* __restrict__ gamma,
    const float* __restrict__ beta, const float* __restrict__ resf,
    float* __restrict__ outf, short* __restrict__ outbf)
{
  constexpr int KC = (CIN + 31) / 32;   // 32-wide k-chunks per row
  constexpr int DCH = CIN / 8;          // real 16B chunks per row
  constexpr int NT = COUT_ / 16;

  const int lane = threadIdx.x;
  const int lm = lane & 15;
  const int quad = lane >> 4;
  const int base = blockIdx.x * (MT * 16);

  int rrow[MT];
  bool rok[MT];
  #pragma unroll
  for (int i = 0; i < MT; ++i) {
    rrow[i] = base + i * 16 + lm;
    rok[i] = rrow[i] < nrows;
  }

  f32x4 acc[MT][NT];
  #pragma unroll
  for (int i = 0; i < MT; ++i)
    #pragma unroll
    for (int t = 0; t < NT; ++t) {
      f32x4 z = {0.f, 0.f, 0.f, 0.f};
      acc[i][t] = z;
    }

  const short8 zero8 = {0, 0, 0, 0, 0, 0, 0, 0};

  auto loadIdx = [&](int (&id)[MT], int k) {
    #pragma unroll
    for (int i = 0; i < MT; ++i)
      id[i] = (k < KOFF && rok[i]) ? nbr[(size_t)rrow[i] * KOFF + k] : -1;
  };

  auto loadA = [&](short8 (&pa)[MT][KC], const int (&id)[MT]) {
    #pragma unroll
    for (int i = 0; i < MT; ++i) {
      const int safe = (id[i] < 0) ? 0 : id[i];     // in-bounds address always
      const bool ok = id[i] >= 0;
      const short* src = finbf + (size_t)safe * CIN;
      #pragma unroll
      for (int q = 0; q < KC; ++q) {
        const int ch = q * 4 + quad;
        short8 v = zero8;
        if (ch < DCH) v = *(const short8*)(src + ch * 8);
        pa[i][q] = ok ? v : zero8;
      }
    }
  };

  auto computeK = [&](const short8 (&pa)[MT][KC], int k) {
    const short* wb = WbfF + ((size_t)k * KC * NT) * 512 + lane * 8;
    #pragma unroll
    for (int q = 0; q < KC; ++q) {
      #pragma unroll
      for (int t = 0; t < NT; ++t) {
        short8 bfr = *(const short8*)(wb + (q * NT + t) * 512);
        #pragma unroll
        for (int i = 0; i < MT; ++i)
          acc[i][t] = __builtin_amdgcn_mfma_f32_16x16x32_bf16(pa[i][q], bfr,
                                                              acc[i][t], 0, 0, 0);
      }
    }
  };

  // ---- depth-3 software pipeline over k (27 = 9*3, no tail) ----
  int ia[MT], ib[MT], ic[MT];
  short8 paA[MT][KC], paB[MT][KC], paC[MT][KC];

  loadIdx(ia, 0); loadIdx(ib, 1); loadIdx(ic, 2);
  loadA(paA, ia); loadIdx(ia, 3);
  loadA(paB, ib); loadIdx(ib, 4);

  for (int kk = 0; kk < KOFF; kk += 3) {
    loadA(paC, ic); loadIdx(ic, kk + 5);
    computeK(paA, kk);
    loadA(paA, ia); loadIdx(ia, kk + 6);   // A(kk+3); k>=27 -> idx=-1 -> zeros
    computeK(paB, kk + 1);
    loadA(paB, ib); loadIdx(ib, kk + 7);   // A(kk+4)
    computeK(paC, kk + 2);
  }

  // ---- epilogue ----
  #pragma unroll
  for (int i = 0; i < MT; ++i) {
    int rbase = base + i * 16 + quad * 4;
    #pragma unroll
    for (int t = 0; t < NT; ++t) {
      int cc = t * 16 + lm;
      float g = gamma[cc], b = beta[cc];
      #pragma unroll
      for (int rg = 0; rg < 4; ++rg) {
        int row = rbase + rg;
        if (row >= nrows) continue;
        float v = acc[i][t][rg];
        if (MODE == 0) {
          outf[(size_t)row * COUT_ + cc] = fmaxf(fmaf(v, g, b), 0.f);
        } else if (MODE == 1) {
          outbf[(size_t)row * COUT_ + cc] = bf16r(fmaxf(fmaf(v, g, b), 0.f));
        } else if (MODE == 2) {
          float o = fmaxf(fmaf(v, g, b), 0.f) + resf[(size_t)row * C2 + cc];
          outf[(size_t)row * CM + 16 + cc] = o;
          outbf[(size_t)row * CM + 16 + cc] = bf16r(o);
        } else if (MODE == 3) {
          float o = fmaxf(fmaf(v, g, b) + resf[(size_t)row * COUT_ + cc], 0.f);
          outf[(size_t)row * COUT_ + cc] = o;
          outbf[(size_t)row * COUT_ + cc] = bf16r(o);
        } else {
          float o = fmaxf(fmaf(v, g, b) + resf[(size_t)row * COUT_ + cc], 0.f);
          outbf[(size_t)row * COUT_ + cc] = bf16r(o);
        }
      }
    }
  }
}

// ---------------------------------------------------------------------------
extern "C" void kernel_launch(void* const* d_in, const int* in_sizes, int n_in,
                              void* d_out, int out_size, void* d_ws, size_t ws_size,
                              hipStream_t stream) {
  const float* x3d  = (const float*)d_in[0];
  const float* f2d  = (const float*)d_in[1];
  const int*   nn   = (const int*)d_in[2];
  const int*   nbr  = (const int*)d_in[3];
  const int*   nbds = (const int*)d_in[4];
  const float* W3d  = (const float*)d_in[5];
  const float* g3d  = (const float*)d_in[6];
  const float* b3d  = (const float*)d_in[7];
  const float* Wg   = (const float*)d_in[8];
  const float* bg   = (const float*)d_in[9];
  const float* Wc   = (const float*)d_in[10];
  const float* bc   = (const float*)d_in[11];
  const float* Wp   = (const float*)d_in[12];
  const float* W2d  = (const float*)d_in[13];
  const float* g2d  = (const float*)d_in[14];
  const float* b2d  = (const float*)d_in[15];
  const float* Wm1  = (const float*)d_in[16];
  const float* gm1  = (const float*)d_in[17];
  const float* bm1  = (const float*)d_in[18];
  const float* Wm2  = (const float*)d_in[19];
  const float* gm2  = (const float*)d_in[20];
  const float* bm2  = (const float*)d_in[21];
  const float* Wa1  = (const float*)d_in[22];
  const float* ga1  = (const float*)d_in[23];
  const float* ba1  = (const float*)d_in[24];
  const float* Wa2  = (const float*)d_in[25];
  const float* ga2  = (const float*)d_in[26];
  const float* ba2  = (const float*)d_in[27];
  const float* Wds  = (const float*)d_in[28];
  const float* gds  = (const float*)d_in[29];
  const float* bds  = (const float*)d_in[30];

  const size_t N = NPTS;
  float* ws = (float*)d_ws;
  float* y3d     = ws;                    // N*16
  short* p2dbf   = (short*)(ws + N * 16); // N*64 bf16
  float* cross2d = ws + N * 48;           // N*64
  float* mix     = ws + N * 112;          // N*80
  short* mixbf   = (short*)(ws + N * 192);// N*80 bf16
  short* tmp1bf  = (short*)(ws + N * 232);// N*80 bf16
  float* hbuf    = ws + N * 272;          // N*80
  short* hbufbf  = (short*)(ws + N * 352);// N*80 bf16
  short* abufbf  = (short*)ws;            // N*80 bf16 (reuses y3d+p2dbf)
  // fragment-ordered bf16 weights at tail
  short* wtail  = (short*)(ws + N * 392);
  short* WbfF2d = wtail;                   // 27*2*4*512 = 110592
  short* WbfFm1 = WbfF2d + 110592;         // 27*3*5*512 = 207360
  short* WbfFm2 = WbfFm1 + 207360;
  short* WbfFa1 = WbfFm2 + 207360;
  short* WbfFa2 = WbfFa1 + 207360;
  short* WbfFds = WbfFa2 + 207360;         // 27*3*6*512 = 248832
  short* WpF    = WbfFds + 248832;         // 18432

  // ---- weight prep ----
  wfrag_kernel<<<(110592 + 255) / 256, 256, 0, stream>>>(W2d, WbfF2d, 64, 64, 2);
  wfrag_kernel<<<(207360 + 255) / 256, 256, 0, stream>>>(Wm1, WbfFm1, 80, 80, 3);
  wfrag_kernel<<<(207360 + 255) / 256, 256, 0, stream>>>(Wm2, WbfFm2, 80, 80, 3);
  wfrag_kernel<<<(207360 + 255) / 256, 256, 0, stream>>>(Wa1, WbfFa1, 80, 80, 3);
  wfrag_kernel<<<(207360 + 255) / 256, 256, 0, stream>>>(Wa2, WbfFa2, 80, 80, 3);
  wfrag_kernel<<<(248832 + 255) / 256, 256, 0, stream>>>(Wds, WbfFds, 80, 96, 3);
  wpfrag_kernel<<<(9 * 4 * 64 * 8 + 255) / 256, 256, 0, stream>>>(Wp, WpF);

  conv3d_bnrelu_kernel<<<NPTS / 16, 256, 0, stream>>>(x3d, nbr, W3d, g3d, b3d,
                                                      y3d, mix, mixbf);
  gate_cross_mfma_kernel<<<NPTS / 32, 256, 0, stream>>>(y3d, f2d, nn, Wg, bg,
                                                        Wc, bc, WpF, p2dbf,
                                                        cross2d);

  const int gridM2 = (NPTS + 31) / 32;    // 2500 one-wave blocks (MT=2)
  conv_nolds_kernel<64, 64, 2, 2><<<gridM2, 64, 0, stream>>>(
      p2dbf, nbr, NPTS, WbfF2d, g2d, b2d, cross2d, mix, mixbf);
  conv_nolds_kernel<80, 80, 1, 2><<<gridM2, 64, 0, stream>>>(
      mixbf, nbr, NPTS, WbfFm1, gm1, bm1, nullptr, nullptr, tmp1bf);
  conv_nolds_kernel<80, 80, 3, 2><<<gridM2, 64, 0, stream>>>(
      tmp1bf, nbr, NPTS, WbfFm2, gm2, bm2, mix, hbuf, hbufbf);
  conv_nolds_kernel<80, 80, 1, 2><<<gridM2, 64, 0, stream>>>(
      hbufbf, nbr, NPTS, WbfFa1, ga1, ba1, nullptr, nullptr, tmp1bf);
  conv_nolds_kernel<80, 80, 4, 2><<<gridM2, 64, 0, stream>>>(
      tmp1bf, nbr, NPTS, WbfFa2, ga2, ba2, hbuf, nullptr, abufbf);

  const int gridDS = (NDPTS + 15) / 16;   // 625 one-wave blocks (MT=1)
  conv_nolds_kernel<80, 96, 0, 1><<<gridDS, 64, 0, stream>>>(
      abufbf, nbds, NDPTS, WbfFds, gds, bds, nullptr, (float*)d_out, nullptr);
}